// Round 1
// baseline (370.620 us; speedup 1.0000x reference)
//
#include <hip/hip_runtime.h>
#include <hip/hip_bf16.h>
#include <stdint.h>

// dist[i,j] = ||s_i||^2 + ||t_j||^2 - 2 s_i . t_j
// prep: s -> bf16(-2*s), t -> bf16(t) into d_ws + exact f32 row norms.
// main: 256x256 bf16 MFMA GEMM, 512 threads / 8 waves (2Mx4N, 128x64 per
// wave), BK=32, 4-slot LDS ring (128 KB), depth-2 counted-vmcnt pipeline
// (T3+T4): stage tile t+2 while computing tile t, s_waitcnt vmcnt(8) + raw
// s_barrier per iteration (never vmcnt(0) mid-loop). 16B-chunk XOR swizzle
// keeps ds_read_b128 fragment reads bank-conflict-free. Fused epilogue with
// nontemporal stores; stores drain across block retirement.

typedef __attribute__((ext_vector_type(8))) short short8v;   // 8 bf16 (4 VGPRs)
typedef __attribute__((ext_vector_type(4))) float f32x4;     // 4 fp32 acc

static __device__ __forceinline__ unsigned short f32_to_bf16_rne(float f) {
    unsigned int u = __float_as_uint(f);
    unsigned int lsb = (u >> 16) & 1u;
    u += 0x7fffu + lsb;
    return (unsigned short)(u >> 16);
}

static __device__ __forceinline__ void async_load16(const void* g, void* l) {
    __builtin_amdgcn_global_load_lds(
        (const __attribute__((address_space(1))) void*)g,
        (__attribute__((address_space(3))) void*)l,
        16, 0, 0);
}

// One wave per row (D must be 512): 8 f32/lane, norm + scaled bf16 conversion.
__global__ __launch_bounds__(256) void prep_kernel(const float* __restrict__ x,
                                                   unsigned short* __restrict__ xb,
                                                   float* __restrict__ nrm,
                                                   float scale) {
    const int tid  = threadIdx.x;
    const int wid  = tid >> 6;
    const int lane = tid & 63;
    const int row  = blockIdx.x * 4 + wid;
    const float* xr = x + (size_t)row * 512;

    float4 v0 = ((const float4*)xr)[lane * 2 + 0];
    float4 v1 = ((const float4*)xr)[lane * 2 + 1];

    float ss = v0.x * v0.x + v0.y * v0.y + v0.z * v0.z + v0.w * v0.w
             + v1.x * v1.x + v1.y * v1.y + v1.z * v1.z + v1.w * v1.w;
#pragma unroll
    for (int off = 32; off > 0; off >>= 1) ss += __shfl_down(ss, off, 64);
    if (lane == 0) nrm[row] = ss;

    unsigned short u[8];
    float vals[8] = {v0.x, v0.y, v0.z, v0.w, v1.x, v1.y, v1.z, v1.w};
#pragma unroll
    for (int e = 0; e < 8; ++e) u[e] = f32_to_bf16_rne(vals[e] * scale);
    unsigned int w0 = (unsigned)u[0] | ((unsigned)u[1] << 16);
    unsigned int w1 = (unsigned)u[2] | ((unsigned)u[3] << 16);
    unsigned int w2 = (unsigned)u[4] | ((unsigned)u[5] << 16);
    unsigned int w3 = (unsigned)u[6] | ((unsigned)u[7] << 16);
    uint4 pk = make_uint4(w0, w1, w2, w3);
    ((uint4*)(xb + (size_t)row * 512))[lane] = pk;
}

#define BM 256
#define BK 32
#define NSLOT 4
// LDS ring: A = [4 slots][256 rows][32 bf16] = 64 KB, B same -> 128 KB total.
// Slot t is overwritten by the stage issued at iteration t+2 (reuse distance
// 4), so the single per-iteration barrier separates its last readers (iter
// t-2, pre-barrier(t-1)) from the overwriting stage (iter t, post-barrier
// (t-1)). vmcnt(8) keeps the 2 newest tiles' 8 loads in flight.
// Swizzle: row = 64 B = 4 chunks of 16 B; LDS slot (row, c) holds global
// chunk c ^ (row&3). Staging stays lane-contiguous (global_load_lds
// wave-uniform-dest requirement, m104/m108); fragment reads per wave cover
// each 1 KB span bijectively -> conflict-free ds_read_b128.

__global__ __launch_bounds__(512, 2) void dist_mfma(const unsigned short* __restrict__ sb,
                                                    const unsigned short* __restrict__ tb,
                                                    const float* __restrict__ ssq,
                                                    const float* __restrict__ tsq,
                                                    float* __restrict__ out,
                                                    int N, int Q, int D) {
    __shared__ __align__(16) unsigned short lds[2 * NSLOT * 256 * 32];  // 128 KB

    const int tid  = threadIdx.x;
    const int wid  = tid >> 6;
    const int lane = tid & 63;
    const int quad = lane >> 4;
    const int r    = lane & 15;
    const int wr   = wid >> 2;     // 0..1
    const int wc   = wid & 3;      // 0..3
    const int m_w  = wr * 128;     // wave's m offset in tile
    const int n_w  = wc * 64;      // wave's n offset in tile

    // block -> (bm,bn) with 8x8 supertile swizzle for L2 locality
    const int bid = blockIdx.x;
    const int nBm = N / BM, nBn = Q / BM;
    int bm, bn;
    if ((nBm & 7) == 0 && (nBn & 7) == 0) {
        const int super = bid >> 6, within = bid & 63;
        const int spr = nBn >> 3;
        const int sm = super / spr, sn = super % spr;
        bm = (sm << 3) + (within >> 3);
        bn = (sn << 3) + (within & 7);
    } else {
        bm = bid / nBn;
        bn = bid - bm * nBn;
    }

    f32x4 acc[8][4];
#pragma unroll
    for (int a = 0; a < 8; ++a)
#pragma unroll
        for (int b = 0; b < 4; ++b) acc[a][b] = (f32x4){0.f, 0.f, 0.f, 0.f};

    // Staging precompute: per matrix per tile = 1024 16B-chunks = 2 insts x
    // 512 threads. Inst i, thread tid covers LDS chunk p = i*512+tid ->
    // row p>>2, slot p&3 -> global chunk (p&3)^(row&3). Per-wave LDS dest
    // base is wave-uniform (lane-contiguous 1 KB).
    const unsigned short* gA[2];
    const unsigned short* gB[2];
    unsigned short* lA[2];
    unsigned short* lB[2];
#pragma unroll
    for (int i = 0; i < 2; ++i) {
        const int p   = i * 512 + tid;
        const int row = p >> 2;
        const int gch = (p & 3) ^ (row & 3);
        gA[i] = sb + (size_t)(bm * BM + row) * D + gch * 8;
        gB[i] = tb + (size_t)(bn * BM + row) * D + gch * 8;
        lA[i] = lds + (i * 512 + wid * 64) * 8;
        lB[i] = lds + NSLOT * 8192 + (i * 512 + wid * 64) * 8;
    }

#define STAGE(t, s) do { const int k0_ = (t) * BK;                  \
        async_load16(gA[0] + k0_, lA[0] + (s) * 8192);              \
        async_load16(gB[0] + k0_, lB[0] + (s) * 8192);              \
        async_load16(gA[1] + k0_, lA[1] + (s) * 8192);              \
        async_load16(gB[1] + k0_, lB[1] + (s) * 8192); } while (0)

    STAGE(0, 0);
    STAGE(1, 1);

    const int NT = D / BK;  // 16
    for (int t = 0; t < NT; ++t) {
        if (t + 2 < NT) STAGE(t + 2, (t + 2) & 3);
        // Counted drain: keep the 2 newest tiles' loads (8) in flight;
        // wait only for tile t's 4 loads. Tail iterations drain 4 -> 0.
        if (t < NT - 2) {
            asm volatile("s_waitcnt vmcnt(8) lgkmcnt(0)" ::: "memory");
        } else if (t == NT - 2) {
            asm volatile("s_waitcnt vmcnt(4) lgkmcnt(0)" ::: "memory");
        } else {
            asm volatile("s_waitcnt vmcnt(0) lgkmcnt(0)" ::: "memory");
        }
        __builtin_amdgcn_sched_barrier(0);
        __builtin_amdgcn_s_barrier();
        __builtin_amdgcn_sched_barrier(0);

        const unsigned short* ba = lds + (t & 3) * 8192;
        const unsigned short* bb = lds + NSLOT * 8192 + (t & 3) * 8192;
        short8v aF[8], bF[4];
#pragma unroll
        for (int im = 0; im < 8; ++im) {
            const int row = m_w + im * 16 + r;
            const int cp  = quad ^ (row & 3);
            aF[im] = *(const short8v*)(ba + row * 32 + cp * 8);
        }
#pragma unroll
        for (int in = 0; in < 4; ++in) {
            const int row = n_w + in * 16 + r;
            const int cp  = quad ^ (row & 3);
            bF[in] = *(const short8v*)(bb + row * 32 + cp * 8);
        }
        __builtin_amdgcn_s_setprio(1);
#pragma unroll
        for (int im = 0; im < 8; ++im)
#pragma unroll
            for (int in = 0; in < 4; ++in)
                acc[im][in] = __builtin_amdgcn_mfma_f32_16x16x32_bf16(
                    aF[im], bF[in], acc[im][in], 0, 0, 0);
        __builtin_amdgcn_s_setprio(0);
    }
#undef STAGE

    // epilogue: C/D layout col = lane&15, row = quad*4 + reg. Nontemporal
    // stores keep the (L2/L3-resident) bf16 inputs from being evicted by the
    // 268 MB output stream; stores stay in flight across block retirement.
    const int gm = bm * BM + m_w;
    const int gn = bn * BM + n_w;
    float tq[4];
#pragma unroll
    for (int in = 0; in < 4; ++in) tq[in] = tsq[gn + in * 16 + r];
#pragma unroll
    for (int im = 0; im < 8; ++im) {
#pragma unroll
        for (int j = 0; j < 4; ++j) {
            const int i = gm + im * 16 + quad * 4 + j;
            const float sv = ssq[i];
            float* orow = out + (size_t)i * (size_t)Q + gn;
#pragma unroll
            for (int in = 0; in < 4; ++in)
                __builtin_nontemporal_store(sv + tq[in] + acc[im][in][j],
                                            &orow[in * 16 + r]);
        }
    }
}

// Correctness fallback if d_ws is too small for the bf16 copies or shapes
// don't fit the tiled path.
__global__ void dist_fallback(const float* __restrict__ s, const float* __restrict__ t,
                              float* __restrict__ out, int N, int Q, int D) {
    __shared__ float ls[16][17], lt[16][17];
    const int tj = threadIdx.x, ti = threadIdx.y;
    const int i = blockIdx.y * 16 + ti, j = blockIdx.x * 16 + tj;
    float cross = 0.f, ssq = 0.f, tsq = 0.f;
    for (int k0 = 0; k0 < D; k0 += 16) {
        __syncthreads();
        ls[ti][tj] = s[(size_t)(blockIdx.y * 16 + ti) * D + k0 + tj];
        lt[ti][tj] = t[(size_t)(blockIdx.x * 16 + ti) * D + k0 + tj];
        __syncthreads();
#pragma unroll
        for (int kk = 0; kk < 16; ++kk) {
            float a = ls[ti][kk], b = lt[tj][kk];
            cross += a * b; ssq += a * a; tsq += b * b;
        }
    }
    out[(size_t)i * Q + j] = ssq + tsq - 2.f * cross;
}

extern "C" void kernel_launch(void* const* d_in, const int* in_sizes, int n_in,
                              void* d_out, int out_size, void* d_ws, size_t ws_size,
                              hipStream_t stream) {
    const float* s = (const float*)d_in[0];
    const float* t = (const float*)d_in[1];
    float* out = (float*)d_out;
    const int D = 512;
    const int N = in_sizes[0] / D;  // 8192
    const int Q = in_sizes[1] / D;  // 8192

    const size_t need = ((size_t)N + (size_t)Q) * D * sizeof(unsigned short)
                      + ((size_t)N + (size_t)Q) * sizeof(float);

    if (ws_size >= need && D == 512 && (N % BM) == 0 && (Q % BM) == 0) {
        unsigned short* sb = (unsigned short*)d_ws;
        unsigned short* tb = sb + (size_t)N * D;
        float* ssq = (float*)(tb + (size_t)Q * D);
        float* tsq = ssq + N;
        prep_kernel<<<N / 4, 256, 0, stream>>>(s, sb, ssq, -2.0f);
        prep_kernel<<<Q / 4, 256, 0, stream>>>(t, tb, tsq, 1.0f);
        const int blocks = (N / BM) * (Q / BM);
        dist_mfma<<<blocks, 512, 0, stream>>>(sb, tb, ssq, tsq, out, N, Q, D);
    } else {
        dim3 g(Q / 16, N / 16), b(16, 16);
        dist_fallback<<<g, b, 0, stream>>>(s, t, out, N, Q, D);
    }
}

// Round 2
// 359.379 us; speedup vs baseline: 1.0313x; 1.0313x over previous
//
#include <hip/hip_runtime.h>
#include <hip/hip_bf16.h>
#include <stdint.h>

// dist[i,j] = ||s_i||^2 + ||t_j||^2 - 2 s_i . t_j
// prep: s -> bf16(-2*s), t -> bf16(t) into d_ws + exact f32 row norms.
// main: m201-style 8-phase 256x256 bf16 MFMA GEMM. 512 threads / 8 waves
// (2Mx4N, 128x64 per wave), BK=64 K-tiles, double-buffered 128 KB LDS.
// Per K-tile: 4 phases, each {ds_read quadrant frags; stage 1 half-tile;
// barrier; lgkmcnt(0); 16 MFMA (setprio-wrapped); barrier}. vmcnt(2) once
// per K-tile (after next-prefetch issue, never 0 mid-loop). 16B-chunk XOR
// swizzle (slot = chunk ^ (row&7)) keeps ds_read_b128 conflict-free while
// global_load_lds dests stay lane-contiguous (source-side pre-swizzle).
// Round-1 lesson: coarse 1-phase + counted vmcnt was -12% (m196/m233 regime:
// without per-phase interleave, LDS and MFMA serialize).

typedef __attribute__((ext_vector_type(8))) short short8v;   // 8 bf16 (4 VGPRs)
typedef __attribute__((ext_vector_type(4))) float f32x4;     // 4 fp32 acc

static __device__ __forceinline__ unsigned short f32_to_bf16_rne(float f) {
    unsigned int u = __float_as_uint(f);
    unsigned int lsb = (u >> 16) & 1u;
    u += 0x7fffu + lsb;
    return (unsigned short)(u >> 16);
}

static __device__ __forceinline__ void async_load16(const void* g, void* l) {
    __builtin_amdgcn_global_load_lds(
        (const __attribute__((address_space(1))) void*)g,
        (__attribute__((address_space(3))) void*)l,
        16, 0, 0);
}

// One wave per row (D must be 512): 8 f32/lane, norm + scaled bf16 conversion.
__global__ __launch_bounds__(256) void prep_kernel(const float* __restrict__ x,
                                                   unsigned short* __restrict__ xb,
                                                   float* __restrict__ nrm,
                                                   float scale) {
    const int tid  = threadIdx.x;
    const int wid  = tid >> 6;
    const int lane = tid & 63;
    const int row  = blockIdx.x * 4 + wid;
    const float* xr = x + (size_t)row * 512;

    float4 v0 = ((const float4*)xr)[lane * 2 + 0];
    float4 v1 = ((const float4*)xr)[lane * 2 + 1];

    float ss = v0.x * v0.x + v0.y * v0.y + v0.z * v0.z + v0.w * v0.w
             + v1.x * v1.x + v1.y * v1.y + v1.z * v1.z + v1.w * v1.w;
#pragma unroll
    for (int off = 32; off > 0; off >>= 1) ss += __shfl_down(ss, off, 64);
    if (lane == 0) nrm[row] = ss;

    unsigned short u[8];
    float vals[8] = {v0.x, v0.y, v0.z, v0.w, v1.x, v1.y, v1.z, v1.w};
#pragma unroll
    for (int e = 0; e < 8; ++e) u[e] = f32_to_bf16_rne(vals[e] * scale);
    unsigned int w0 = (unsigned)u[0] | ((unsigned)u[1] << 16);
    unsigned int w1 = (unsigned)u[2] | ((unsigned)u[3] << 16);
    unsigned int w2 = (unsigned)u[4] | ((unsigned)u[5] << 16);
    unsigned int w3 = (unsigned)u[6] | ((unsigned)u[7] << 16);
    uint4 pk = make_uint4(w0, w1, w2, w3);
    ((uint4*)(xb + (size_t)row * 512))[lane] = pk;
}

#define BM 256
#define BKT 64
#define NTILE 8   // D / BKT with D = 512

// LDS: [2 buf][A 256x64 | B 256x64] bf16 = 2 * 64 KB = 128 KB.
// Half-tiles (16 KB = 2 global_load_lds x 512 thr x 16 B):
//   h0 = A rows 0-127, h1 = A rows 128-255, h2 = B rows 0-127, h3 = B 128-255.
// Stage schedule for tile t (buf b = t&1), per phase:
//   P0: ds A-quad0 + B-pair0 | stage h1(t+1)->b^1 | MFMA acc[0..3][0..1]
//   P1: ds B-pair1           | stage h2(t+1)->b^1 | MFMA acc[0..3][2..3]
//   P2: ds A-quad1           | stage h3(t+1)->b^1 | MFMA acc[4..7][0..1]
//   P3: (no ds)              | stage h0(t+2)->b   | vmcnt(2) | MFMA acc[4..7][2..3]
// Race audit: each half's writers issue >=1 barrier after its last readers'
// lgkm-certified drain; vmcnt(2) after the P3 stage drains ALL of tile t+1's
// 8 loads while keeping h0(t+2) in flight. Prologue: h0-h3(0), h0(1),
// vmcnt(2), barrier. Tail: t=NTILE-2 -> vmcnt(0); t=NTILE-1 -> no stages.

__global__ __launch_bounds__(512, 2) void dist_mfma(const unsigned short* __restrict__ sb,
                                                    const unsigned short* __restrict__ tb,
                                                    const float* __restrict__ ssq,
                                                    const float* __restrict__ tsq,
                                                    float* __restrict__ out,
                                                    int N, int Q, int D) {
    __shared__ __align__(16) unsigned short lds[2 * 32768];  // 128 KB

    const int tid  = threadIdx.x;
    const int wid  = tid >> 6;
    const int lane = tid & 63;
    const int quad = lane >> 4;
    const int r    = lane & 15;
    const int wr   = wid >> 2;     // 0..1 -> m offset wr*128
    const int wc   = wid & 3;      // 0..3 -> n offset wc*64

    // block -> (bm,bn) with 8x8 supertile swizzle for L2 locality
    const int bid = blockIdx.x;
    const int nBm = N / BM, nBn = Q / BM;
    int bm, bn;
    if ((nBm & 7) == 0 && (nBn & 7) == 0) {
        const int super = bid >> 6, within = bid & 63;
        const int spr = nBn >> 3;
        const int sm = super / spr, sn = super % spr;
        bm = (sm << 3) + (within >> 3);
        bn = (sn << 3) + (within & 7);
    } else {
        bm = bid / nBn;
        bn = bid - bm * nBn;
    }

    f32x4 acc[8][4];
#pragma unroll
    for (int a = 0; a < 8; ++a)
#pragma unroll
        for (int b = 0; b < 4; ++b) acc[a][b] = (f32x4){0.f, 0.f, 0.f, 0.f};

    // Staging: half h, inst i covers 16B-chunks p = i*512+tid ->
    // row = p>>3 (0..127), LDS slot = tid&7, global chunk = slot ^ (row&7).
    const unsigned short* gH[4][2];
#pragma unroll
    for (int i = 0; i < 2; ++i) {
        const int row = (i * 512 + tid) >> 3;
        const int gch = (tid ^ row) & 7;
        gH[0][i] = sb + (size_t)(bm * BM +       row) * 512 + gch * 8;
        gH[1][i] = sb + (size_t)(bm * BM + 128 + row) * 512 + gch * 8;
        gH[2][i] = tb + (size_t)(bn * BM +       row) * 512 + gch * 8;
        gH[3][i] = tb + (size_t)(bn * BM + 128 + row) * 512 + gch * 8;
    }
    const int ldsl = tid * 8;  // shorts

#define STAGE_HALF(h, t, b) do {                                              \
        async_load16(gH[h][0] + (t) * BKT,                                    \
                     lds + (b) * 32768 + (h) * 8192 + ldsl);                  \
        async_load16(gH[h][1] + (t) * BKT,                                    \
                     lds + (b) * 32768 + (h) * 8192 + 4096 + ldsl);           \
    } while (0)

    // Fragment read bases (shorts). row&7 == r&7 for all frag rows.
    const int aBase = (wr * 128 + r) * 64;          // A: + im*1024 (+4096 quad1)
    const int bBase = 16384 + (wc * 64 + r) * 64;   // B: + in*1024
    int cSw[2];
#pragma unroll
    for (int kk = 0; kk < 2; ++kk) cSw[kk] = ((kk * 4 + quad) ^ (r & 7)) * 8;

    // prologue: tile0 fully + h0 of tile1; keep h0(1) in flight.
    STAGE_HALF(0, 0, 0); STAGE_HALF(1, 0, 0);
    STAGE_HALF(2, 0, 0); STAGE_HALF(3, 0, 0);
    STAGE_HALF(0, 1, 1);
    asm volatile("s_waitcnt vmcnt(2)" ::: "memory");
    __builtin_amdgcn_s_barrier();

#define SYNC_PRE() do {                                                       \
        __builtin_amdgcn_s_barrier();                                         \
        asm volatile("s_waitcnt lgkmcnt(0)" ::: "memory");                    \
        __builtin_amdgcn_sched_barrier(0);                                    \
        __builtin_amdgcn_s_setprio(1);                                        \
    } while (0)
#define SYNC_POST() do {                                                      \
        __builtin_amdgcn_s_setprio(0);                                        \
        __builtin_amdgcn_s_barrier();                                         \
    } while (0)

    short8v aF[4][2], bF[4][2];

#pragma unroll 2
    for (int t = 0; t < NTILE; ++t) {
        const int b = t & 1;
        const unsigned short* bufA = lds + b * 32768;

        // ---- P0: A-quad0 (im 0-3) + B-pair0 (in 0-1); MFMA acc[0..3][0..1]
#pragma unroll
        for (int im = 0; im < 4; ++im)
#pragma unroll
            for (int kk = 0; kk < 2; ++kk)
                aF[im][kk] = *(const short8v*)(bufA + aBase + im * 1024 + cSw[kk]);
#pragma unroll
        for (int in = 0; in < 2; ++in)
#pragma unroll
            for (int kk = 0; kk < 2; ++kk)
                bF[in][kk] = *(const short8v*)(bufA + bBase + in * 1024 + cSw[kk]);
        if (t + 1 < NTILE) STAGE_HALF(1, t + 1, b ^ 1);
        SYNC_PRE();
#pragma unroll
        for (int im = 0; im < 4; ++im)
#pragma unroll
            for (int in = 0; in < 2; ++in)
#pragma unroll
                for (int kk = 0; kk < 2; ++kk)
                    acc[im][in] = __builtin_amdgcn_mfma_f32_16x16x32_bf16(
                        aF[im][kk], bF[in][kk], acc[im][in], 0, 0, 0);
        SYNC_POST();

        // ---- P1: B-pair1 (in 2-3); MFMA acc[0..3][2..3]
#pragma unroll
        for (int in = 0; in < 2; ++in)
#pragma unroll
            for (int kk = 0; kk < 2; ++kk)
                bF[2 + in][kk] = *(const short8v*)(bufA + bBase + (2 + in) * 1024 + cSw[kk]);
        if (t + 1 < NTILE) STAGE_HALF(2, t + 1, b ^ 1);
        SYNC_PRE();
#pragma unroll
        for (int im = 0; im < 4; ++im)
#pragma unroll
            for (int in = 0; in < 2; ++in)
#pragma unroll
                for (int kk = 0; kk < 2; ++kk)
                    acc[im][2 + in] = __builtin_amdgcn_mfma_f32_16x16x32_bf16(
                        aF[im][kk], bF[2 + in][kk], acc[im][2 + in], 0, 0, 0);
        SYNC_POST();

        // ---- P2: A-quad1 (im 4-7, reuse aF regs); MFMA acc[4..7][0..1]
#pragma unroll
        for (int im = 0; im < 4; ++im)
#pragma unroll
            for (int kk = 0; kk < 2; ++kk)
                aF[im][kk] = *(const short8v*)(bufA + aBase + 4096 + im * 1024 + cSw[kk]);
        if (t + 1 < NTILE) STAGE_HALF(3, t + 1, b ^ 1);
        SYNC_PRE();
#pragma unroll
        for (int im = 0; im < 4; ++im)
#pragma unroll
            for (int in = 0; in < 2; ++in)
#pragma unroll
                for (int kk = 0; kk < 2; ++kk)
                    acc[4 + im][in] = __builtin_amdgcn_mfma_f32_16x16x32_bf16(
                        aF[im][kk], bF[in][kk], acc[4 + im][in], 0, 0, 0);
        SYNC_POST();

        // ---- P3: no ds; prefetch h0(t+2) into current buf; per-tile vmcnt
        if (t + 2 < NTILE) STAGE_HALF(0, t + 2, b);
        if (t < NTILE - 2) {
            asm volatile("s_waitcnt vmcnt(2)" ::: "memory");
        } else if (t == NTILE - 2) {
            asm volatile("s_waitcnt vmcnt(0)" ::: "memory");
        }
        SYNC_PRE();
#pragma unroll
        for (int im = 0; im < 4; ++im)
#pragma unroll
            for (int in = 0; in < 2; ++in)
#pragma unroll
                for (int kk = 0; kk < 2; ++kk)
                    acc[4 + im][2 + in] = __builtin_amdgcn_mfma_f32_16x16x32_bf16(
                        aF[im][kk], bF[2 + in][kk], acc[4 + im][2 + in], 0, 0, 0);
        SYNC_POST();
    }
#undef STAGE_HALF
#undef SYNC_PRE
#undef SYNC_POST

    // epilogue: C/D layout col = lane&15, row = quad*4 + reg. Nontemporal
    // stores: keep L2/L3-resident bf16 inputs from being evicted by the
    // 268 MB output stream; stores drain across block retirement.
    const int gm = bm * BM + wr * 128;
    const int gn = bn * BM + wc * 64;
    float tq[4];
#pragma unroll
    for (int in = 0; in < 4; ++in) tq[in] = tsq[gn + in * 16 + r];
#pragma unroll
    for (int im = 0; im < 8; ++im) {
#pragma unroll
        for (int j = 0; j < 4; ++j) {
            const int i = gm + im * 16 + quad * 4 + j;
            const float sv = ssq[i];
            float* orow = out + (size_t)i * (size_t)Q + gn;
#pragma unroll
            for (int in = 0; in < 4; ++in)
                __builtin_nontemporal_store(sv + tq[in] + acc[im][in][j],
                                            &orow[in * 16 + r]);
        }
    }
}

// Correctness fallback if d_ws is too small for the bf16 copies or shapes
// don't fit the tiled path.
__global__ void dist_fallback(const float* __restrict__ s, const float* __restrict__ t,
                              float* __restrict__ out, int N, int Q, int D) {
    __shared__ float ls[16][17], lt[16][17];
    const int tj = threadIdx.x, ti = threadIdx.y;
    const int i = blockIdx.y * 16 + ti, j = blockIdx.x * 16 + tj;
    float cross = 0.f, ssq = 0.f, tsq = 0.f;
    for (int k0 = 0; k0 < D; k0 += 16) {
        __syncthreads();
        ls[ti][tj] = s[(size_t)(blockIdx.y * 16 + ti) * D + k0 + tj];
        lt[ti][tj] = t[(size_t)(blockIdx.x * 16 + ti) * D + k0 + tj];
        __syncthreads();
#pragma unroll
        for (int kk = 0; kk < 16; ++kk) {
            float a = ls[ti][kk], b = lt[tj][kk];
            cross += a * b; ssq += a * a; tsq += b * b;
        }
    }
    out[(size_t)i * Q + j] = ssq + tsq - 2.f * cross;
}

extern "C" void kernel_launch(void* const* d_in, const int* in_sizes, int n_in,
                              void* d_out, int out_size, void* d_ws, size_t ws_size,
                              hipStream_t stream) {
    const float* s = (const float*)d_in[0];
    const float* t = (const float*)d_in[1];
    float* out = (float*)d_out;
    const int D = 512;
    const int N = in_sizes[0] / D;  // 8192
    const int Q = in_sizes[1] / D;  // 8192

    const size_t need = ((size_t)N + (size_t)Q) * D * sizeof(unsigned short)
                      + ((size_t)N + (size_t)Q) * sizeof(float);

    if (ws_size >= need && D == 512 && (N % BM) == 0 && (Q % BM) == 0) {
        unsigned short* sb = (unsigned short*)d_ws;
        unsigned short* tb = sb + (size_t)N * D;
        float* ssq = (float*)(tb + (size_t)Q * D);
        float* tsq = ssq + N;
        prep_kernel<<<N / 4, 256, 0, stream>>>(s, sb, ssq, -2.0f);
        prep_kernel<<<Q / 4, 256, 0, stream>>>(t, tb, tsq, 1.0f);
        const int blocks = (N / BM) * (Q / BM);
        dist_mfma<<<blocks, 512, 0, stream>>>(sb, tb, ssq, tsq, out, N, Q, D);
    } else {
        dim3 g(Q / 16, N / 16), b(16, 16);
        dist_fallback<<<g, b, 0, stream>>>(s, t, out, N, Q, D);
    }
}